// Round 7
// baseline (915.677 us; speedup 1.0000x reference)
//
#include <hip/hip_runtime.h>
#include <hip/hip_cooperative_groups.h>

namespace cg = cooperative_groups;

// PCEN: x (B=32, T=4000, C=128) fp32.
//   ema[t] = w*x[t] + (1-w)*ema[t-1],  ema[0] = x[0]
//   out = (x / (FLOOR + ema)^alpha + delta)^(1/root) - delta^(1/root)
//
// R12: fused cooperative kernel, COHERENCE-FIXED.
// R7/R11 failed correctness (absmax 3.28): S/E staging rows passed between
// phases through plain loads/stores were served stale from non-coherent
// per-XCD L2s (Guideline 16) — the 3-kernel version was only correct because
// inter-dispatch barriers flush L2. Fix: ALL cross-block staging (S rows,
// E rows) now uses agent-scope atomics (cache-bypass, device-coherent);
// fences around both grid.sync()s; cooperative-launch return code checked
// with fallback to the harness-verified 3-kernel path.
// Phases:
//   P1: per chunk j, S_j = sum_i w(1-w)^{L-1-i} x[i]  -> out row j*CHUNK+1
//   P2: per (b,c) wave, Kogge-Stone scan e_{j+1} = A e_j + S_j -> E_j rows
//   P3: per chunk j, run recurrence from exact E_j + transcendental epilogue
// Grid: 2048 blocks x 128 thr, 16KB LDS -> needs 8 blocks/CU (cap 10 by LDS,
// 16 waves/CU needs VGPR<=128, enforced by __launch_bounds__(128,4)).

#define FLOOR_EPS 1e-12f

constexpr int Bn = 32;
constexpr int Tn = 4000;
constexpr int Cn = 128;
constexpr int NCHUNK = 125;          // 125 * 32 = 4000
constexpr int CHUNK  = 32;
constexpr int NTASK  = Bn * NCHUNK;  // 4000 chunk-tasks
constexpr int GRID   = 2048;

__device__ __forceinline__ void agent_store(float* p, float v) {
    __hip_atomic_store(p, v, __ATOMIC_RELAXED, __HIP_MEMORY_SCOPE_AGENT);
}
__device__ __forceinline__ float agent_load(const float* p) {
    return __hip_atomic_load((float*)p, __ATOMIC_RELAXED, __HIP_MEMORY_SCOPE_AGENT);
}

__global__ __launch_bounds__(Cn, 4) void kfused(
    const float* __restrict__ x,
    const float* __restrict__ alpha_p,
    const float* __restrict__ delta_p,
    const float* __restrict__ root_p,
    const float* __restrict__ w_p,
    float* __restrict__ out)
{
    __shared__ float tile[CHUNK * Cn];           // 16 KB, reused across phases
    const int tid = threadIdx.x;
    const int bid = blockIdx.x;
    cg::grid_group grid = cg::this_grid();

    const int c = tid;
    const float w   = fminf(fmaxf(w_p[c], 0.0f), 1.0f);
    const float omw = 1.0f - w;

    // ---------------- P1: local weighted sums ----------------
    for (int task = bid; task < NTASK; task += GRID) {
        const int j = task % NCHUNK;
        const int b = task / NCHUNK;
        const size_t base = ((size_t)b * Tn + (size_t)j * CHUNK) * (size_t)Cn;

        const float4* __restrict__ g4 = (const float4*)(x + base);
        float4* t4 = (float4*)tile;
        #pragma unroll
        for (int k = 0; k < 8; ++k)
            t4[k * Cn + tid] = g4[k * Cn + tid];
        __syncthreads();

        float s = 0.0f;
        #pragma unroll
        for (int k = 0; k < CHUNK; ++k)          // LDS column read: lanes
            s = fmaf(omw, s, w * tile[k * Cn + c]);  // consecutive -> no conflict
        agent_store(&out[base + Cn + c], s);     // S_j row, device-coherent
        __syncthreads();                         // tile reused next iteration
    }

    __threadfence();                             // release
    grid.sync();
    __threadfence();                             // acquire

    // ---------------- P2: chunk-state scan (4096 waves) ----------------
    {
        const int wid  = bid * 2 + (tid >> 6);   // 0..4095
        const int lane = tid & 63;
        const int b  = wid >> 7;                 // 0..31
        const int cc = wid & 127;                // 0..127

        const float w2   = fminf(fmaxf(w_p[cc], 0.0f), 1.0f);
        const float omw2 = 1.0f - w2;
        // A = omw^CHUNK (omw=0 -> log2=-inf -> A=0 correct; omw=1 -> A=1)
        const float A = __builtin_exp2f((float)CHUNK * __builtin_log2f(omw2));

        const float* __restrict__ sb = out + (size_t)b * Tn * Cn + cc;
        float* __restrict__ eb       = out + (size_t)b * Tn * Cn + cc;

        // segment 1: chunks j = lane (0..63); segment 2: j = 64+lane (<125)
        float s1 = agent_load(&sb[((size_t)lane * CHUNK + 1) * Cn]);
        float a1 = A;
        const int j2 = 64 + lane;
        float s2 = (j2 < NCHUNK) ? agent_load(&sb[((size_t)j2 * CHUNK + 1) * Cn]) : 0.0f;
        float a2 = (j2 < NCHUNK) ? A : 1.0f;

        // inclusive Kogge-Stone scan of affine transforms (a,s): e -> a*e + s
        #pragma unroll
        for (int r = 1; r < 64; r <<= 1) {
            float ts = __shfl_up(s1, r, 64);
            float ta = __shfl_up(a1, r, 64);
            if (lane >= r) { s1 = fmaf(a1, ts, s1); a1 *= ta; }
            ts = __shfl_up(s2, r, 64);
            ta = __shfl_up(a2, r, 64);
            if (lane >= r) { s2 = fmaf(a2, ts, s2); a2 *= ta; }
        }

        const float e0 = x[(size_t)b * Tn * Cn + cc];   // ema init = x[b,0,c]
        const float E1 = fmaf(a1, e0, s1);              // E_{lane+1}
        const float E64 = __shfl(E1, 63, 64);           // carry into segment 2
        const float E2 = fmaf(a2, E64, s2);             // E_{65+lane}

        if (lane == 0) agent_store(&eb[0], e0);         // E_0 (row 0)
        agent_store(&eb[(size_t)(lane + 1) * CHUNK * Cn], E1);   // E_1..E_64
        if (lane + 65 < NCHUNK)
            agent_store(&eb[(size_t)(lane + 65) * CHUNK * Cn], E2); // E_65..E_124
    }

    __threadfence();                             // release
    grid.sync();
    __threadfence();                             // acquire

    // ---------------- P3: apply recurrence + epilogue ----------------
    const float alpha  = fminf(alpha_p[c], 1.0f);
    const float root   = fmaxf(root_p[c], 1.0f);
    const float delta  = delta_p[c];
    const float oor    = 1.0f / root;
    const float droot  = __builtin_exp2f(oor * __builtin_log2f(delta));
    const float nalpha = -alpha;

    for (int task = bid; task < NTASK; task += GRID) {
        const int j = task % NCHUNK;
        const int b = task / NCHUNK;
        const size_t base = ((size_t)b * Tn + (size_t)j * CHUNK) * (size_t)Cn;

        const float4* __restrict__ g4 = (const float4*)(x + base);
        float4* t4 = (float4*)tile;
        #pragma unroll
        for (int k = 0; k < 8; ++k)
            t4[k * Cn + tid] = g4[k * Cn + tid];

        const float E = agent_load(&out[base + c]);  // exact E_j, coherent
        __syncthreads();

        float acc = E;
        #pragma unroll
        for (int k = 0; k < CHUNK; ++k) {
            const float xv = tile[k * Cn + c];
            acc = fmaf(omw, acc, w * xv);
            const float l  = __builtin_log2f(FLOOR_EPS + acc);
            const float t1 = xv * __builtin_exp2f(nalpha * l);
            tile[k * Cn + c] =
                __builtin_exp2f(oor * __builtin_log2f(t1 + delta)) - droot;
        }
        __syncthreads();

        float4* o4 = (float4*)(out + base);
        #pragma unroll
        for (int k = 0; k < 8; ++k)
            o4[k * Cn + tid] = t4[k * Cn + tid];
        __syncthreads();                 // tile reused next iteration
    }
}

// ================= fallback path: harness-verified 3-kernel (R6) ==========
__global__ __launch_bounds__(Cn) void k1_localsum(
    const float* __restrict__ x,
    const float* __restrict__ w_p,
    float* __restrict__ out)
{
    __shared__ float tile[CHUNK * Cn];
    const int tid = threadIdx.x;
    const int j = blockIdx.x;
    const int b = blockIdx.y;
    const size_t base = ((size_t)b * Tn + (size_t)j * CHUNK) * (size_t)Cn;

    const float4* __restrict__ g4 = (const float4*)(x + base);
    float4* t4 = (float4*)tile;
    #pragma unroll
    for (int k = 0; k < 8; ++k)
        t4[k * Cn + tid] = g4[k * Cn + tid];
    __syncthreads();

    const int c = tid;
    const float w   = fminf(fmaxf(w_p[c], 0.0f), 1.0f);
    const float omw = 1.0f - w;
    float s = 0.0f;
    #pragma unroll
    for (int k = 0; k < CHUNK; ++k)
        s = fmaf(omw, s, w * tile[k * Cn + c]);
    out[base + Cn + c] = s;
}

__global__ __launch_bounds__(256) void k2_scan(
    const float* __restrict__ x,
    const float* __restrict__ w_p,
    float* __restrict__ out)
{
    const int wid  = (blockIdx.x * 256 + threadIdx.x) >> 6;
    const int lane = threadIdx.x & 63;
    const int b = wid >> 7;
    const int c = wid & 127;

    const float w   = fminf(fmaxf(w_p[c], 0.0f), 1.0f);
    const float omw = 1.0f - w;
    const float A = __builtin_exp2f((float)CHUNK * __builtin_log2f(omw));

    const float* __restrict__ sb = out + (size_t)b * Tn * Cn + c;
    float* __restrict__ eb       = out + (size_t)b * Tn * Cn + c;

    float s1 = sb[((size_t)lane * CHUNK + 1) * Cn];
    float a1 = A;
    const int j2 = 64 + lane;
    float s2 = (j2 < NCHUNK) ? sb[((size_t)j2 * CHUNK + 1) * Cn] : 0.0f;
    float a2 = (j2 < NCHUNK) ? A : 1.0f;

    #pragma unroll
    for (int r = 1; r < 64; r <<= 1) {
        float ts = __shfl_up(s1, r, 64);
        float ta = __shfl_up(a1, r, 64);
        if (lane >= r) { s1 = fmaf(a1, ts, s1); a1 *= ta; }
        ts = __shfl_up(s2, r, 64);
        ta = __shfl_up(a2, r, 64);
        if (lane >= r) { s2 = fmaf(a2, ts, s2); a2 *= ta; }
    }

    const float e0 = x[(size_t)b * Tn * Cn + c];
    const float E1 = fmaf(a1, e0, s1);
    const float E64 = __shfl(E1, 63, 64);
    const float E2 = fmaf(a2, E64, s2);

    if (lane == 0) eb[0] = e0;
    eb[(size_t)(lane + 1) * CHUNK * Cn] = E1;
    if (lane + 65 < NCHUNK)
        eb[(size_t)(lane + 65) * CHUNK * Cn] = E2;
}

__global__ __launch_bounds__(Cn) void k3_apply(
    const float* __restrict__ x,
    const float* __restrict__ alpha_p,
    const float* __restrict__ delta_p,
    const float* __restrict__ root_p,
    const float* __restrict__ w_p,
    float* __restrict__ out)
{
    __shared__ float tile[CHUNK * Cn];
    const int tid = threadIdx.x;
    const int j = blockIdx.x;
    const int b = blockIdx.y;
    const size_t base = ((size_t)b * Tn + (size_t)j * CHUNK) * (size_t)Cn;

    const float4* __restrict__ g4 = (const float4*)(x + base);
    float4* t4 = (float4*)tile;
    #pragma unroll
    for (int k = 0; k < 8; ++k)
        t4[k * Cn + tid] = g4[k * Cn + tid];

    const int c = tid;
    const float alpha  = fminf(alpha_p[c], 1.0f);
    const float root   = fmaxf(root_p[c], 1.0f);
    const float delta  = delta_p[c];
    const float oor    = 1.0f / root;
    const float droot  = __builtin_exp2f(oor * __builtin_log2f(delta));
    const float nalpha = -alpha;
    const float w      = fminf(fmaxf(w_p[c], 0.0f), 1.0f);
    const float omw    = 1.0f - w;

    const float E = out[base + c];
    __syncthreads();

    float acc = E;
    #pragma unroll
    for (int k = 0; k < CHUNK; ++k) {
        const float xv = tile[k * Cn + c];
        acc = fmaf(omw, acc, w * xv);
        const float l  = __builtin_log2f(FLOOR_EPS + acc);
        const float t1 = xv * __builtin_exp2f(nalpha * l);
        tile[k * Cn + c] =
            __builtin_exp2f(oor * __builtin_log2f(t1 + delta)) - droot;
    }
    __syncthreads();

    float4* o4 = (float4*)(out + base);
    #pragma unroll
    for (int k = 0; k < 8; ++k)
        o4[k * Cn + tid] = t4[k * Cn + tid];
}

extern "C" void kernel_launch(void* const* d_in, const int* in_sizes, int n_in,
                              void* d_out, int out_size, void* d_ws, size_t ws_size,
                              hipStream_t stream) {
    const float* x     = (const float*)d_in[0];
    const float* alpha = (const float*)d_in[1];
    const float* delta = (const float*)d_in[2];
    const float* root  = (const float*)d_in[3];
    const float* ew    = (const float*)d_in[4];
    float* out = (float*)d_out;

    void* args[] = { (void*)&x, (void*)&alpha, (void*)&delta,
                     (void*)&root, (void*)&ew, (void*)&out };
    hipError_t err = hipLaunchCooperativeKernel((const void*)kfused,
                                                dim3(GRID), dim3(Cn),
                                                args, 0, stream);
    if (err != hipSuccess) {
        // proven 3-kernel path (R6, 133.7 us) — correctness via dispatch
        // boundaries' L2 writeback/invalidate
        dim3 grid(NCHUNK, Bn, 1);
        k1_localsum<<<grid, Cn, 0, stream>>>(x, ew, out);
        k2_scan<<<dim3((Bn * Cn * 64) / 256), 256, 0, stream>>>(x, ew, out);
        k3_apply<<<grid, Cn, 0, stream>>>(x, alpha, delta, root, ew, out);
    }
}

// Round 8
// 145.267 us; speedup vs baseline: 6.3034x; 6.3034x over previous
//
#include <hip/hip_runtime.h>

// PCEN: x (B=32, T=4000, C=128) fp32.
//   ema[t] = w*x[t] + (1-w)*ema[t-1],  ema[0] = x[0]
//   out = (x / (FLOOR + ema)^alpha + delta)^(1/root) - delta^(1/root)
//
// R13: TWO-dispatch chunked scan (k2 eliminated).
// R12 post-mortem: fused coop kernel passed but 838us with VALUBusy 2.1% /
// HBM 2.4% -> grid.sync() spin at 2048 blocks costs O(100s us). Grid-wide
// sync abandoned. The 41us/256MB fills in top-5 are harness ws-poison =>
// d_ws exists and is large; fixed ~41us/iter tax we can't remove.
// New structure:
//   D1: per chunk j, S_j = sum_i w(1-w)^{L-1-i} x[i] -> ws[b][j][c] (coalesced)
//   D2: block (b,j) computes E_j itself by folding the S-prefix
//       (e=e0; for i<j: e = A*e + S_i  — <=124 L2-hit loads, overlapped with
//       x-tile staging), then recurrence + transcendental epilogue.
// All cross-block data crosses a DISPATCH boundary (hardware-coherent, same
// as the passing R6 path). No same-dispatch races: D2 reads only ws + x,
// writes only its own out region. Fallback to verified 3-kernel path if
// ws_size is too small.

#define FLOOR_EPS 1e-12f

constexpr int Bn = 32;
constexpr int Tn = 4000;
constexpr int Cn = 128;
constexpr int NCHUNK = 125;          // 125 * 32 = 4000
constexpr int CHUNK  = 32;

// ---------------- D1: local weighted sums -> ws ----------------
__global__ __launch_bounds__(Cn) void d1_localsum(
    const float* __restrict__ x,
    const float* __restrict__ w_p,
    float* __restrict__ S)
{
    __shared__ float tile[CHUNK * Cn];           // 16 KB
    const int tid = threadIdx.x;
    const int j = blockIdx.x;
    const int b = blockIdx.y;
    const size_t base = ((size_t)b * Tn + (size_t)j * CHUNK) * (size_t)Cn;

    const float4* __restrict__ g4 = (const float4*)(x + base);
    float4* t4 = (float4*)tile;
    #pragma unroll
    for (int k = 0; k < 8; ++k)
        t4[k * Cn + tid] = g4[k * Cn + tid];
    __syncthreads();

    const int c = tid;
    const float w   = fminf(fmaxf(w_p[c], 0.0f), 1.0f);
    const float omw = 1.0f - w;
    float s = 0.0f;
    #pragma unroll
    for (int k = 0; k < CHUNK; ++k)
        s = fmaf(omw, s, w * tile[k * Cn + c]);
    S[((size_t)b * NCHUNK + j) * Cn + c] = s;    // coalesced 512B row
}

// ---------------- D2: prefix-fold E_j + recurrence + epilogue ----------------
__global__ __launch_bounds__(Cn) void d2_apply(
    const float* __restrict__ x,
    const float* __restrict__ alpha_p,
    const float* __restrict__ delta_p,
    const float* __restrict__ root_p,
    const float* __restrict__ w_p,
    const float* __restrict__ S,
    float* __restrict__ out)
{
    __shared__ float tile[CHUNK * Cn];           // 16 KB: x chunk then results
    const int tid = threadIdx.x;
    const int j = blockIdx.x;
    const int b = blockIdx.y;
    const size_t base = ((size_t)b * Tn + (size_t)j * CHUNK) * (size_t)Cn;

    // stage x chunk (16B/lane, in flight while we fold the prefix)
    const float4* __restrict__ g4 = (const float4*)(x + base);
    float4* t4 = (float4*)tile;
    #pragma unroll
    for (int k = 0; k < 8; ++k)
        t4[k * Cn + tid] = g4[k * Cn + tid];

    const int c = tid;
    const float w   = fminf(fmaxf(w_p[c], 0.0f), 1.0f);
    const float omw = 1.0f - w;
    // A = omw^CHUNK (omw=0 -> log2=-inf -> A=0 correct; omw=1 -> A=1)
    const float A = __builtin_exp2f((float)CHUNK * __builtin_log2f(omw));

    // E_j = A^j e0 + sum_{i<j} A^{j-1-i} S_i, computed as serial fold.
    // S rows are 2MB total, read by all 125 j-blocks per b -> L2-resident.
    float e = x[(size_t)b * Tn * Cn + c];        // e0 = x[b,0,c] (L3-cached row)
    const float* __restrict__ sp = S + (size_t)b * NCHUNK * Cn + c;
    #pragma unroll 4
    for (int i = 0; i < j; ++i)
        e = fmaf(A, e, sp[(size_t)i * Cn]);

    const float alpha  = fminf(alpha_p[c], 1.0f);
    const float root   = fmaxf(root_p[c], 1.0f);
    const float delta  = delta_p[c];
    const float oor    = 1.0f / root;
    const float droot  = __builtin_exp2f(oor * __builtin_log2f(delta));
    const float nalpha = -alpha;
    __syncthreads();                             // x tile ready

    float acc = e;                               // exact E_j
    #pragma unroll
    for (int k = 0; k < CHUNK; ++k) {
        const float xv = tile[k * Cn + c];       // conflict-free column read
        acc = fmaf(omw, acc, w * xv);
        const float l  = __builtin_log2f(FLOOR_EPS + acc);
        const float t1 = xv * __builtin_exp2f(nalpha * l);
        tile[k * Cn + c] =
            __builtin_exp2f(oor * __builtin_log2f(t1 + delta)) - droot;
    }
    __syncthreads();

    float4* o4 = (float4*)(out + base);
    #pragma unroll
    for (int k = 0; k < 8; ++k)
        o4[k * Cn + tid] = t4[k * Cn + tid];
}

// ============ fallback: harness-verified 3-kernel path (R6, 133.7us) ========
__global__ __launch_bounds__(Cn) void k1_localsum(
    const float* __restrict__ x,
    const float* __restrict__ w_p,
    float* __restrict__ out)
{
    __shared__ float tile[CHUNK * Cn];
    const int tid = threadIdx.x;
    const int j = blockIdx.x;
    const int b = blockIdx.y;
    const size_t base = ((size_t)b * Tn + (size_t)j * CHUNK) * (size_t)Cn;

    const float4* __restrict__ g4 = (const float4*)(x + base);
    float4* t4 = (float4*)tile;
    #pragma unroll
    for (int k = 0; k < 8; ++k)
        t4[k * Cn + tid] = g4[k * Cn + tid];
    __syncthreads();

    const int c = tid;
    const float w   = fminf(fmaxf(w_p[c], 0.0f), 1.0f);
    const float omw = 1.0f - w;
    float s = 0.0f;
    #pragma unroll
    for (int k = 0; k < CHUNK; ++k)
        s = fmaf(omw, s, w * tile[k * Cn + c]);
    out[base + Cn + c] = s;
}

__global__ __launch_bounds__(256) void k2_scan(
    const float* __restrict__ x,
    const float* __restrict__ w_p,
    float* __restrict__ out)
{
    const int wid  = (blockIdx.x * 256 + threadIdx.x) >> 6;
    const int lane = threadIdx.x & 63;
    const int b = wid >> 7;
    const int c = wid & 127;

    const float w   = fminf(fmaxf(w_p[c], 0.0f), 1.0f);
    const float omw = 1.0f - w;
    const float A = __builtin_exp2f((float)CHUNK * __builtin_log2f(omw));

    const float* __restrict__ sb = out + (size_t)b * Tn * Cn + c;
    float* __restrict__ eb       = out + (size_t)b * Tn * Cn + c;

    float s1 = sb[((size_t)lane * CHUNK + 1) * Cn];
    float a1 = A;
    const int j2 = 64 + lane;
    float s2 = (j2 < NCHUNK) ? sb[((size_t)j2 * CHUNK + 1) * Cn] : 0.0f;
    float a2 = (j2 < NCHUNK) ? A : 1.0f;

    #pragma unroll
    for (int r = 1; r < 64; r <<= 1) {
        float ts = __shfl_up(s1, r, 64);
        float ta = __shfl_up(a1, r, 64);
        if (lane >= r) { s1 = fmaf(a1, ts, s1); a1 *= ta; }
        ts = __shfl_up(s2, r, 64);
        ta = __shfl_up(a2, r, 64);
        if (lane >= r) { s2 = fmaf(a2, ts, s2); a2 *= ta; }
    }

    const float e0 = x[(size_t)b * Tn * Cn + c];
    const float E1 = fmaf(a1, e0, s1);
    const float E64 = __shfl(E1, 63, 64);
    const float E2 = fmaf(a2, E64, s2);

    if (lane == 0) eb[0] = e0;
    eb[(size_t)(lane + 1) * CHUNK * Cn] = E1;
    if (lane + 65 < NCHUNK)
        eb[(size_t)(lane + 65) * CHUNK * Cn] = E2;
}

__global__ __launch_bounds__(Cn) void k3_apply(
    const float* __restrict__ x,
    const float* __restrict__ alpha_p,
    const float* __restrict__ delta_p,
    const float* __restrict__ root_p,
    const float* __restrict__ w_p,
    float* __restrict__ out)
{
    __shared__ float tile[CHUNK * Cn];
    const int tid = threadIdx.x;
    const int j = blockIdx.x;
    const int b = blockIdx.y;
    const size_t base = ((size_t)b * Tn + (size_t)j * CHUNK) * (size_t)Cn;

    const float4* __restrict__ g4 = (const float4*)(x + base);
    float4* t4 = (float4*)tile;
    #pragma unroll
    for (int k = 0; k < 8; ++k)
        t4[k * Cn + tid] = g4[k * Cn + tid];

    const int c = tid;
    const float alpha  = fminf(alpha_p[c], 1.0f);
    const float root   = fmaxf(root_p[c], 1.0f);
    const float delta  = delta_p[c];
    const float oor    = 1.0f / root;
    const float droot  = __builtin_exp2f(oor * __builtin_log2f(delta));
    const float nalpha = -alpha;
    const float w      = fminf(fmaxf(w_p[c], 0.0f), 1.0f);
    const float omw    = 1.0f - w;

    const float E = out[base + c];
    __syncthreads();

    float acc = E;
    #pragma unroll
    for (int k = 0; k < CHUNK; ++k) {
        const float xv = tile[k * Cn + c];
        acc = fmaf(omw, acc, w * xv);
        const float l  = __builtin_log2f(FLOOR_EPS + acc);
        const float t1 = xv * __builtin_exp2f(nalpha * l);
        tile[k * Cn + c] =
            __builtin_exp2f(oor * __builtin_log2f(t1 + delta)) - droot;
    }
    __syncthreads();

    float4* o4 = (float4*)(out + base);
    #pragma unroll
    for (int k = 0; k < 8; ++k)
        o4[k * Cn + tid] = t4[k * Cn + tid];
}

extern "C" void kernel_launch(void* const* d_in, const int* in_sizes, int n_in,
                              void* d_out, int out_size, void* d_ws, size_t ws_size,
                              hipStream_t stream) {
    const float* x     = (const float*)d_in[0];
    const float* alpha = (const float*)d_in[1];
    const float* delta = (const float*)d_in[2];
    const float* root  = (const float*)d_in[3];
    const float* ew    = (const float*)d_in[4];
    float* out = (float*)d_out;

    const size_t ws_needed = (size_t)Bn * NCHUNK * Cn * sizeof(float); // 2.0 MB
    dim3 grid(NCHUNK, Bn, 1);

    if (d_ws != nullptr && ws_size >= ws_needed) {
        float* S = (float*)d_ws;
        d1_localsum<<<grid, Cn, 0, stream>>>(x, ew, S);
        d2_apply<<<grid, Cn, 0, stream>>>(x, alpha, delta, root, ew, S, out);
    } else {
        // proven 3-kernel path (R6): staging inside out, coherence via
        // dispatch boundaries
        k1_localsum<<<grid, Cn, 0, stream>>>(x, ew, out);
        k2_scan<<<dim3((Bn * Cn * 64) / 256), 256, 0, stream>>>(x, ew, out);
        k3_apply<<<grid, Cn, 0, stream>>>(x, alpha, delta, root, ew, out);
    }
}

// Round 9
// 140.462 us; speedup vs baseline: 6.5190x; 1.0342x over previous
//
#include <hip/hip_runtime.h>

// PCEN: x (B=32, T=4000, C=128) fp32.
//   ema[t] = w*x[t] + (1-w)*ema[t-1],  ema[0] = x[0]
//   out = (x / (FLOOR + ema)^alpha + delta)^(1/root) - delta^(1/root)
//
// R14: THREE-dispatch, all-coalesced chunked scan.
// R13 post-mortem: d2's per-block serial prefix fold (O(j) L2 loads,
// linear work imbalance) cost ~28us of stall on a 17us-traffic kernel
// (44.8us, 30% BW, 32% VALU, 27% occ). Fix: scan ONCE in a tiny middle
// dispatch over the coalesced ws layout; d2 reads its exact E_j row with
// one coalesced load. Every d2 block now does identical work.
//   D1 : per chunk (b,j): S_j = sum_i w(1-w)^{L-1-i} x[i] -> ws[b][j][c]
//   D15: per b: in-place serial scan  s=row[j]; row[j]=e; e=A*e+s
//        (loads address-independent -> pipelined; E_j = ema state at chunk-j
//        start replaces S_j in ws)
//   D2 : per chunk (b,j): read E_j row, run recurrence + epilogue, write out.
// Cross-kernel data crosses dispatch boundaries only (hardware-coherent,
// same as the passing R6/R13 paths). Fallback to verified 3-kernel R6 path
// if ws_size < 2MB.

#define FLOOR_EPS 1e-12f

constexpr int Bn = 32;
constexpr int Tn = 4000;
constexpr int Cn = 128;
constexpr int NCHUNK = 125;          // 125 * 32 = 4000
constexpr int CHUNK  = 32;

// ---------------- D1: local weighted sums -> ws ----------------
__global__ __launch_bounds__(Cn) void d1_localsum(
    const float* __restrict__ x,
    const float* __restrict__ w_p,
    float* __restrict__ S)
{
    __shared__ float tile[CHUNK * Cn];           // 16 KB
    const int tid = threadIdx.x;
    const int j = blockIdx.x;
    const int b = blockIdx.y;
    const size_t base = ((size_t)b * Tn + (size_t)j * CHUNK) * (size_t)Cn;

    const float4* __restrict__ g4 = (const float4*)(x + base);
    float4* t4 = (float4*)tile;
    #pragma unroll
    for (int k = 0; k < 8; ++k)
        t4[k * Cn + tid] = g4[k * Cn + tid];
    __syncthreads();

    const int c = tid;
    const float w   = fminf(fmaxf(w_p[c], 0.0f), 1.0f);
    const float omw = 1.0f - w;
    float s = 0.0f;
    #pragma unroll
    for (int k = 0; k < CHUNK; ++k)
        s = fmaf(omw, s, w * tile[k * Cn + c]);
    S[((size_t)b * NCHUNK + j) * Cn + c] = s;    // coalesced 512B row
}

// ---------------- D15: in-place chunk-state scan (S_j -> E_j) -------------
__global__ __launch_bounds__(Cn) void d15_scan(
    const float* __restrict__ x,
    const float* __restrict__ w_p,
    float* __restrict__ ws)
{
    const int c = threadIdx.x;
    const int b = blockIdx.x;

    const float w   = fminf(fmaxf(w_p[c], 0.0f), 1.0f);
    const float omw = 1.0f - w;
    // A = omw^CHUNK (omw=0 -> log2=-inf -> A=0 correct; omw=1 -> A=1)
    const float A = __builtin_exp2f((float)CHUNK * __builtin_log2f(omw));

    float e = x[(size_t)b * Tn * Cn + c];        // e0 = x[b,0,c]
    float* __restrict__ row = ws + (size_t)b * NCHUNK * Cn + c;

    // in-place: ws row j becomes E_j (ema state at start of chunk j);
    // loads are address-independent -> pipeline under the 4-cyc FMA chain
    #pragma unroll 5
    for (int jj = 0; jj < NCHUNK; ++jj) {
        const float s = row[(size_t)jj * Cn];
        row[(size_t)jj * Cn] = e;
        e = fmaf(A, e, s);
    }
}

// ---------------- D2: recurrence from exact E_j + epilogue ----------------
__global__ __launch_bounds__(Cn) void d2_apply(
    const float* __restrict__ x,
    const float* __restrict__ alpha_p,
    const float* __restrict__ delta_p,
    const float* __restrict__ root_p,
    const float* __restrict__ w_p,
    const float* __restrict__ E,
    float* __restrict__ out)
{
    __shared__ float tile[CHUNK * Cn];           // 16 KB: x chunk then results
    const int tid = threadIdx.x;
    const int j = blockIdx.x;
    const int b = blockIdx.y;
    const size_t base = ((size_t)b * Tn + (size_t)j * CHUNK) * (size_t)Cn;

    // stage x chunk (16B/lane)
    const float4* __restrict__ g4 = (const float4*)(x + base);
    float4* t4 = (float4*)tile;
    #pragma unroll
    for (int k = 0; k < 8; ++k)
        t4[k * Cn + tid] = g4[k * Cn + tid];

    const int c = tid;
    const float w   = fminf(fmaxf(w_p[c], 0.0f), 1.0f);
    const float omw = 1.0f - w;
    const float e   = E[((size_t)b * NCHUNK + j) * Cn + c];  // coalesced row

    const float alpha  = fminf(alpha_p[c], 1.0f);
    const float root   = fmaxf(root_p[c], 1.0f);
    const float delta  = delta_p[c];
    const float oor    = 1.0f / root;
    const float droot  = __builtin_exp2f(oor * __builtin_log2f(delta));
    const float nalpha = -alpha;
    __syncthreads();                             // x tile ready

    float acc = e;                               // exact E_j
    #pragma unroll
    for (int k = 0; k < CHUNK; ++k) {
        const float xv = tile[k * Cn + c];       // conflict-free column read
        acc = fmaf(omw, acc, w * xv);
        const float l  = __builtin_log2f(FLOOR_EPS + acc);
        const float t1 = xv * __builtin_exp2f(nalpha * l);
        tile[k * Cn + c] =
            __builtin_exp2f(oor * __builtin_log2f(t1 + delta)) - droot;
    }
    __syncthreads();

    float4* o4 = (float4*)(out + base);
    #pragma unroll
    for (int k = 0; k < 8; ++k)
        o4[k * Cn + tid] = t4[k * Cn + tid];
}

// ============ fallback: harness-verified 3-kernel path (R6, 133.7us) ========
__global__ __launch_bounds__(Cn) void k1_localsum(
    const float* __restrict__ x,
    const float* __restrict__ w_p,
    float* __restrict__ out)
{
    __shared__ float tile[CHUNK * Cn];
    const int tid = threadIdx.x;
    const int j = blockIdx.x;
    const int b = blockIdx.y;
    const size_t base = ((size_t)b * Tn + (size_t)j * CHUNK) * (size_t)Cn;

    const float4* __restrict__ g4 = (const float4*)(x + base);
    float4* t4 = (float4*)tile;
    #pragma unroll
    for (int k = 0; k < 8; ++k)
        t4[k * Cn + tid] = g4[k * Cn + tid];
    __syncthreads();

    const int c = tid;
    const float w   = fminf(fmaxf(w_p[c], 0.0f), 1.0f);
    const float omw = 1.0f - w;
    float s = 0.0f;
    #pragma unroll
    for (int k = 0; k < CHUNK; ++k)
        s = fmaf(omw, s, w * tile[k * Cn + c]);
    out[base + Cn + c] = s;
}

__global__ __launch_bounds__(256) void k2_scan(
    const float* __restrict__ x,
    const float* __restrict__ w_p,
    float* __restrict__ out)
{
    const int wid  = (blockIdx.x * 256 + threadIdx.x) >> 6;
    const int lane = threadIdx.x & 63;
    const int b = wid >> 7;
    const int c = wid & 127;

    const float w   = fminf(fmaxf(w_p[c], 0.0f), 1.0f);
    const float omw = 1.0f - w;
    const float A = __builtin_exp2f((float)CHUNK * __builtin_log2f(omw));

    const float* __restrict__ sb = out + (size_t)b * Tn * Cn + c;
    float* __restrict__ eb       = out + (size_t)b * Tn * Cn + c;

    float s1 = sb[((size_t)lane * CHUNK + 1) * Cn];
    float a1 = A;
    const int j2 = 64 + lane;
    float s2 = (j2 < NCHUNK) ? sb[((size_t)j2 * CHUNK + 1) * Cn] : 0.0f;
    float a2 = (j2 < NCHUNK) ? A : 1.0f;

    #pragma unroll
    for (int r = 1; r < 64; r <<= 1) {
        float ts = __shfl_up(s1, r, 64);
        float ta = __shfl_up(a1, r, 64);
        if (lane >= r) { s1 = fmaf(a1, ts, s1); a1 *= ta; }
        ts = __shfl_up(s2, r, 64);
        ta = __shfl_up(a2, r, 64);
        if (lane >= r) { s2 = fmaf(a2, ts, s2); a2 *= ta; }
    }

    const float e0 = x[(size_t)b * Tn * Cn + c];
    const float E1 = fmaf(a1, e0, s1);
    const float E64 = __shfl(E1, 63, 64);
    const float E2 = fmaf(a2, E64, s2);

    if (lane == 0) eb[0] = e0;
    eb[(size_t)(lane + 1) * CHUNK * Cn] = E1;
    if (lane + 65 < NCHUNK)
        eb[(size_t)(lane + 65) * CHUNK * Cn] = E2;
}

__global__ __launch_bounds__(Cn) void k3_apply(
    const float* __restrict__ x,
    const float* __restrict__ alpha_p,
    const float* __restrict__ delta_p,
    const float* __restrict__ root_p,
    const float* __restrict__ w_p,
    float* __restrict__ out)
{
    __shared__ float tile[CHUNK * Cn];
    const int tid = threadIdx.x;
    const int j = blockIdx.x;
    const int b = blockIdx.y;
    const size_t base = ((size_t)b * Tn + (size_t)j * CHUNK) * (size_t)Cn;

    const float4* __restrict__ g4 = (const float4*)(x + base);
    float4* t4 = (float4*)tile;
    #pragma unroll
    for (int k = 0; k < 8; ++k)
        t4[k * Cn + tid] = g4[k * Cn + tid];

    const int c = tid;
    const float alpha  = fminf(alpha_p[c], 1.0f);
    const float root   = fmaxf(root_p[c], 1.0f);
    const float delta  = delta_p[c];
    const float oor    = 1.0f / root;
    const float droot  = __builtin_exp2f(oor * __builtin_log2f(delta));
    const float nalpha = -alpha;
    const float w      = fminf(fmaxf(w_p[c], 0.0f), 1.0f);
    const float omw    = 1.0f - w;

    const float E = out[base + c];
    __syncthreads();

    float acc = E;
    #pragma unroll
    for (int k = 0; k < CHUNK; ++k) {
        const float xv = tile[k * Cn + c];
        acc = fmaf(omw, acc, w * xv);
        const float l  = __builtin_log2f(FLOOR_EPS + acc);
        const float t1 = xv * __builtin_exp2f(nalpha * l);
        tile[k * Cn + c] =
            __builtin_exp2f(oor * __builtin_log2f(t1 + delta)) - droot;
    }
    __syncthreads();

    float4* o4 = (float4*)(out + base);
    #pragma unroll
    for (int k = 0; k < 8; ++k)
        o4[k * Cn + tid] = t4[k * Cn + tid];
}

extern "C" void kernel_launch(void* const* d_in, const int* in_sizes, int n_in,
                              void* d_out, int out_size, void* d_ws, size_t ws_size,
                              hipStream_t stream) {
    const float* x     = (const float*)d_in[0];
    const float* alpha = (const float*)d_in[1];
    const float* delta = (const float*)d_in[2];
    const float* root  = (const float*)d_in[3];
    const float* ew    = (const float*)d_in[4];
    float* out = (float*)d_out;

    const size_t ws_needed = (size_t)Bn * NCHUNK * Cn * sizeof(float); // 2.0 MB
    dim3 grid(NCHUNK, Bn, 1);

    if (d_ws != nullptr && ws_size >= ws_needed) {
        float* S = (float*)d_ws;
        d1_localsum<<<grid, Cn, 0, stream>>>(x, ew, S);
        d15_scan<<<dim3(Bn), Cn, 0, stream>>>(x, ew, S);   // S -> E in place
        d2_apply<<<grid, Cn, 0, stream>>>(x, alpha, delta, root, ew, S, out);
    } else {
        // proven 3-kernel path (R6): staging inside out, coherence via
        // dispatch boundaries
        k1_localsum<<<grid, Cn, 0, stream>>>(x, ew, out);
        k2_scan<<<dim3((Bn * Cn * 64) / 256), 256, 0, stream>>>(x, ew, out);
        k3_apply<<<grid, Cn, 0, stream>>>(x, alpha, delta, root, ew, out);
    }
}